// Round 3
// baseline (790.100 us; speedup 1.0000x reference)
//
#include <hip/hip_runtime.h>
#include <stdint.h>

// ---------------------------------------------------------------------------
// DWTFeatureModel: pool(2x2) -> 4-level db4 DWT (len 128 -> 154) -> einsum.
// DWT + einsum folded into Weff[b][f][k], k = s*16 + h*4 + w  (k = 0..2047).
// Main kernel: GEMM-style. Block = (8 n, bin b). Thread owns (1 n, 3 f) and
// the FULL k-reduction (no cross-lane shuffles). P staged in LDS from pooled
// x; W chunk staged via async global_load_lds with XOR-swizzle; double-buffered.
// ---------------------------------------------------------------------------

#define NBINS 4
#define NFEAT 48
#define DWT_LEN 154

#define TN 8            // n per block
#define KC 64           // k per chunk
#define NCHUNK 32       // 2048 / KC
#define KROW 68         // KC + 4 pad floats (bank spread for P reads)
#define WBYTES (NFEAT * KC * 4)  // 12288 B per W chunk

#define GLOBAL_AS __attribute__((address_space(1)))
#define LDS_AS __attribute__((address_space(3)))

// H0R = DEC_LO reversed, H1R = DEC_HI reversed (jax conv = correlation)
__device__ __constant__ float c_h0r[8] = {
    0.23037781330885523f,  0.7148465705525415f,   0.6308807679295904f,
   -0.02798376941698385f, -0.18703481171888114f,  0.030841381835986965f,
    0.032883011666982945f, -0.010597401784997278f };
__device__ __constant__ float c_h1r[8] = {
   -0.010597401784997278f, -0.032883011666982945f, 0.030841381835986965f,
    0.18703481171888114f,  -0.02798376941698385f, -0.6308807679295904f,
    0.7148465705525415f,   -0.23037781330885523f };

// Build D[154][128]: column s = dwt_concat(e_s). 2 blocks x 64 columns, LDS.
__global__ void build_dwt_matrix(float* __restrict__ D) {
  __shared__ float work[128 * 64];
  __shared__ float tmp[67 * 64];
  int ls = threadIdx.x;            // 0..63
  int s  = blockIdx.x * 64 + ls;   // global column
  for (int i = 0; i < 128; ++i) work[i * 64 + ls] = (i == s) ? 1.f : 0.f;
  int N = 128;
  const int HI_OFF[4] = {14, 81, 118, 140}; // lo occupies rows 0..13
  for (int lev = 0; lev < 4; ++lev) {
    int out = (N + 7) >> 1;
    int p  = 2 * (out - 1) - N + 8;
    int pl = p >> 1;
    for (int k = 0; k < out; ++k) {
      float lo = 0.f, hi = 0.f;
      #pragma unroll
      for (int l = 0; l < 8; ++l) {
        int idx = 2 * k + l - pl;
        idx = idx < 0 ? -idx : idx;            // reflect (no edge repeat)
        idx = idx >= N ? 2 * N - 2 - idx : idx;
        float v = work[idx * 64 + ls];
        lo += c_h0r[l] * v;
        hi += c_h1r[l] * v;
      }
      tmp[k * 64 + ls] = lo;
      D[(HI_OFF[lev] + k) * 128 + s] = hi;
    }
    for (int k = 0; k < out; ++k) work[k * 64 + ls] = tmp[k * 64 + ls];
    N = out;
  }
  for (int k = 0; k < 14; ++k) D[k * 128 + s] = work[k * 64 + ls];
}

// Weff[bf][s*16+hw] = sum_t conv_w[bf][t][hw] * D[t][s].  192 blocks x 256 thr.
__global__ void build_weff(const float* __restrict__ conv_w,
                           const float* __restrict__ D,
                           float* __restrict__ Weff) {
  int bf = blockIdx.x; // 0..191
  __shared__ float cw[DWT_LEN * 16];
  for (int i = threadIdx.x; i < DWT_LEN * 16; i += blockDim.x)
    cw[i] = conv_w[(size_t)bf * (DWT_LEN * 16) + i];
  __syncthreads();
  int s  = threadIdx.x & 127;
  int h0 = threadIdx.x >> 7; // 0 or 1
  float acc[8] = {0.f, 0.f, 0.f, 0.f, 0.f, 0.f, 0.f, 0.f};
  #pragma unroll 4
  for (int t = 0; t < DWT_LEN; ++t) {
    float d = D[t * 128 + s];
    #pragma unroll
    for (int j = 0; j < 8; ++j) acc[j] += cw[t * 16 + h0 + 2 * j] * d;
  }
  #pragma unroll
  for (int j = 0; j < 8; ++j) {
    int hw = h0 + 2 * j;
    Weff[(size_t)bf * 2048 + s * 16 + hw] = acc[j];
  }
}

// ---------------------------------------------------------------------------
// Main fused kernel. Grid = (n/8)*4 blocks of 128 threads (2 waves).
// Thread (cn = tid&7, cfg = tid>>3) accumulates out[n0+cn][b][3*cfg..+2]
// over all k in registers. Per chunk (64 k = 4 t-rows):
//   stage: x -> regs (prefetched 2 ahead) -> 2x2 pool -> P_lds[8][68]
//          Weff chunk -> W_lds via global_load_lds (swizzled source)
//   compute: 16 k-steps x (1 P b128 + 3 W b128 + 12 FMA), conflict-free.
// ---------------------------------------------------------------------------
__global__ __launch_bounds__(128, 2)
void dwt_feat_main(const float* __restrict__ x,
                   const float* __restrict__ Weff,
                   const float* __restrict__ conv_b,
                   float* __restrict__ out, int n_total) {
  __shared__ __align__(16) float P_lds[2][TN][KROW];
  __shared__ __align__(16) uint8_t W_lds[2][WBYTES];

  const int tid  = threadIdx.x;
  const int wave = tid >> 6;
  const int b    = blockIdx.x & 3;
  const int n0   = (blockIdx.x >> 2) * TN;
  if (n0 >= n_total) return;

  // compute identity: 1 n x 3 f per thread
  const int cn  = tid & 7;
  const int cfg = tid >> 3;        // 0..15
  const int f0  = cfg * 3;

  // staging identity: 16 threads per n, 16 consecutive floats each
  const int sn    = tid >> 4;      // 0..7
  const int idx16 = tid & 15;
  const int t_sub = idx16 >> 2;    // t-row within chunk (0..3)
  const int hq    = idx16 & 3;     // h-pair (0..3)
  const int pk    = t_sub * 16 + hq * 4;  // float offset in P row

  const float* xb =
      x + (size_t)(n0 + sn) * 32768 + (size_t)b * 8192 + idx16 * 16;
  const uint8_t* wb = (const uint8_t*)(Weff + (size_t)b * NFEAT * 2048);

  float4 xr[4];

  // ---- staging helpers -----------------------------------------------------
  auto loadX = [&](int c) {
    const float4* s = (const float4*)(xb + c * 256);
    #pragma unroll
    for (int i = 0; i < 4; ++i) xr[i] = s[i];
  };
  auto stageP = [&](int buf) {
    // xr = 2 h-rows (8 w each) x 2: pool 2x2 -> 4 floats at k_local = pk..pk+3
    float4 p;
    p.x = fmaxf(fmaxf(xr[0].x, xr[0].y), fmaxf(xr[2].x, xr[2].y));
    p.y = fmaxf(fmaxf(xr[0].z, xr[0].w), fmaxf(xr[2].z, xr[2].w));
    p.z = fmaxf(fmaxf(xr[1].x, xr[1].y), fmaxf(xr[3].x, xr[3].y));
    p.w = fmaxf(fmaxf(xr[1].z, xr[1].w), fmaxf(xr[3].z, xr[3].w));
    *(float4*)&P_lds[buf][sn][pk] = p;
  };
  auto stageW = [&](int c, int buf) {
    // W_lds layout: [f][256 B], XOR-swizzled: LDS byte o holds logical byte
    // o ^ ((f&7)<<4)  (f = o>>8). Dest is linear (global_load_lds), source
    // address pre-swizzled. 6 rounds x 128 lanes x 16 B = 12288 B.
    #pragma unroll
    for (int r = 0; r < 6; ++r) {
      uint32_t o = r * 2048 + tid * 16;
      uint32_t f = o >> 8;
      uint32_t inner = (o & 255) ^ ((f & 7) << 4);
      const uint8_t* src = wb + f * 8192 + c * 256 + inner;
      uint8_t* dst = &W_lds[buf][r * 2048 + wave * 1024]; // wave-uniform
      __builtin_amdgcn_global_load_lds(
          (const GLOBAL_AS uint32_t*)src, (LDS_AS uint32_t*)dst, 16, 0, 0);
    }
  };

  // ---- prologue ------------------------------------------------------------
  loadX(0);
  stageW(0, 0);
  stageP(0);       // waits on x(0) loads
  loadX(1);        // prefetch chunk 1 into regs (no wait)
  __syncthreads(); // drains vmcnt (W(0) + x(1)) and lgkm (P writes)

  // swizzled W read bases for this thread's 3 features
  const uint32_t wb0 = (uint32_t)(f0 + 0) << 8, xo0 = (uint32_t)((f0 + 0) & 7) << 4;
  const uint32_t wb1 = (uint32_t)(f0 + 1) << 8, xo1 = (uint32_t)((f0 + 1) & 7) << 4;
  const uint32_t wb2 = (uint32_t)(f0 + 2) << 8, xo2 = (uint32_t)((f0 + 2) & 7) << 4;

  float acc0 = 0.f, acc1 = 0.f, acc2 = 0.f;

  #pragma unroll 2
  for (int c = 0; c < NCHUNK; ++c) {
    const int cur = c & 1;
    if (c + 1 < NCHUNK) {
      stageW(c + 1, cur ^ 1);      // async -> other buffer
      stageP(cur ^ 1);             // pool x(c+1) (in regs) -> other buffer
      if (c + 2 < NCHUNK) loadX(c + 2); // refill regs, consumed next iter
    }
    // compute chunk c: 16 k-steps, all LDS reads bank-conflict-free
    const uint8_t* Wb = W_lds[cur];
    const float*   Pb = P_lds[cur][cn];
    #pragma unroll
    for (int kk = 0; kk < 16; ++kk) {
      float4 p = *(const float4*)(Pb + kk * 4);
      uint32_t kx = (uint32_t)kk << 4;
      float4 w0 = *(const float4*)(Wb + (wb0 | (kx ^ xo0)));
      float4 w1 = *(const float4*)(Wb + (wb1 | (kx ^ xo1)));
      float4 w2 = *(const float4*)(Wb + (wb2 | (kx ^ xo2)));
      acc0 += p.x * w0.x + p.y * w0.y + p.z * w0.z + p.w * w0.w;
      acc1 += p.x * w1.x + p.y * w1.y + p.z * w1.z + p.w * w1.w;
      acc2 += p.x * w2.x + p.y * w2.y + p.z * w2.z + p.w * w2.w;
    }
    __syncthreads(); // chunk c done for all; chunk c+1 staged for next iter
  }

  // ---- epilogue: bias + leaky-relu + store ---------------------------------
  const float* bias = conv_b + b * NFEAT + f0;
  float* o = out + (size_t)(n0 + cn) * (NBINS * NFEAT) + b * NFEAT + f0;
  float v0 = acc0 + bias[0]; o[0] = v0 > 0.f ? v0 : 0.02f * v0;
  float v1 = acc1 + bias[1]; o[1] = v1 > 0.f ? v1 : 0.02f * v1;
  float v2 = acc2 + bias[2]; o[2] = v2 > 0.f ? v2 : 0.02f * v2;
}

extern "C" void kernel_launch(void* const* d_in, const int* in_sizes, int n_in,
                              void* d_out, int out_size, void* d_ws, size_t ws_size,
                              hipStream_t stream) {
  const float* x      = (const float*)d_in[0]; // (n,1,512,8,8)
  const float* conv_w = (const float*)d_in[1]; // (4,48,154,4,4)
  const float* conv_b = (const float*)d_in[2]; // (4,48)
  float* out = (float*)d_out;

  float* D    = (float*)d_ws;            // 154*128 floats = 77 KB
  float* Weff = (float*)d_ws + 32768;    // at 128 KB offset; 1.5 MB

  int n = in_sizes[0] / 32768; // 2048

  build_dwt_matrix<<<2, 64, 0, stream>>>(D);
  build_weff<<<NBINS * NFEAT, 256, 0, stream>>>(conv_w, D, Weff);
  dwt_feat_main<<<(n / TN) * NBINS, 128, 0, stream>>>(x, Weff, conv_b, out, n);
}

// Round 6
// 471.913 us; speedup vs baseline: 1.6742x; 1.6742x over previous
//
#include <hip/hip_runtime.h>
#include <stdint.h>

// ---------------------------------------------------------------------------
// DWTFeatureModel: pool(2x2) -> 4-level db4 DWT (len 128 -> 154) -> einsum.
// DWT + einsum folded into Weff[b][f][k], k = s*16 + h*4 + w  (k = 0..2047).
// Main kernel: block = (8 n, bin b), 256 thr. Thread owns (1 n, 3 f, half-k)
// with the k-reduction fully in registers (no shuffles). Pooled x staged in a
// tiny double-buffered LDS tile; W read directly from L1/L2 (1.5 MB resident).
// ---------------------------------------------------------------------------

#define NBINS 4
#define NFEAT 48
#define DWT_LEN 154

#define TN 8            // n per block
#define CK 128          // k per chunk
#define NCHUNK 16       // 2048 / CK
#define PROW 132        // P row stride in floats (128 + 4 pad)

// H0R = DEC_LO reversed, H1R = DEC_HI reversed (jax conv = correlation)
__device__ __constant__ float c_h0r[8] = {
    0.23037781330885523f,  0.7148465705525415f,   0.6308807679295904f,
   -0.02798376941698385f, -0.18703481171888114f,  0.030841381835986965f,
    0.032883011666982945f, -0.010597401784997278f };
__device__ __constant__ float c_h1r[8] = {
   -0.010597401784997278f, -0.032883011666982945f, 0.030841381835986965f,
    0.18703481171888114f,  -0.02798376941698385f, -0.6308807679295904f,
    0.7148465705525415f,   -0.23037781330885523f };

// Build D[154][128]: column s = dwt_concat(e_s). 2 blocks x 64 columns, LDS.
__global__ void build_dwt_matrix(float* __restrict__ D) {
  __shared__ float work[128 * 64];
  __shared__ float tmp[67 * 64];
  int ls = threadIdx.x;            // 0..63
  int s  = blockIdx.x * 64 + ls;   // global column
  for (int i = 0; i < 128; ++i) work[i * 64 + ls] = (i == s) ? 1.f : 0.f;
  int N = 128;
  const int HI_OFF[4] = {14, 81, 118, 140}; // lo occupies rows 0..13
  for (int lev = 0; lev < 4; ++lev) {
    int out = (N + 7) >> 1;
    int p  = 2 * (out - 1) - N + 8;
    int pl = p >> 1;
    for (int k = 0; k < out; ++k) {
      float lo = 0.f, hi = 0.f;
      #pragma unroll
      for (int l = 0; l < 8; ++l) {
        int idx = 2 * k + l - pl;
        idx = idx < 0 ? -idx : idx;            // reflect (no edge repeat)
        idx = idx >= N ? 2 * N - 2 - idx : idx;
        float v = work[idx * 64 + ls];
        lo += c_h0r[l] * v;
        hi += c_h1r[l] * v;
      }
      tmp[k * 64 + ls] = lo;
      D[(HI_OFF[lev] + k) * 128 + s] = hi;
    }
    for (int k = 0; k < out; ++k) work[k * 64 + ls] = tmp[k * 64 + ls];
    N = out;
  }
  for (int k = 0; k < 14; ++k) D[k * 128 + s] = work[k * 64 + ls];
}

// Weff[bf][s*16+hw] = sum_t conv_w[bf][t][hw] * D[t][s].  192 blocks x 256 thr.
__global__ void build_weff(const float* __restrict__ conv_w,
                           const float* __restrict__ D,
                           float* __restrict__ Weff) {
  int bf = blockIdx.x; // 0..191
  __shared__ float cw[DWT_LEN * 16];
  for (int i = threadIdx.x; i < DWT_LEN * 16; i += blockDim.x)
    cw[i] = conv_w[(size_t)bf * (DWT_LEN * 16) + i];
  __syncthreads();
  int s  = threadIdx.x & 127;
  int h0 = threadIdx.x >> 7; // 0 or 1
  float acc[8] = {0.f, 0.f, 0.f, 0.f, 0.f, 0.f, 0.f, 0.f};
  #pragma unroll 4
  for (int t = 0; t < DWT_LEN; ++t) {
    float d = D[t * 128 + s];
    #pragma unroll
    for (int j = 0; j < 8; ++j) acc[j] += cw[t * 16 + h0 + 2 * j] * d;
  }
  #pragma unroll
  for (int j = 0; j < 8; ++j) {
    int hw = h0 + 2 * j;
    Weff[(size_t)bf * 2048 + s * 16 + hw] = acc[j];
  }
}

// ---------------------------------------------------------------------------
// Main fused kernel. Grid = (n/8)*4 blocks of 256 threads.
// Staging id : sn = tid>>5 (n), s_local = (tid&31)>>2 (time step in chunk),
//              hp = tid&3 (h-pair). Thread loads 16 contiguous floats
//              (rows 2hp, 2hp+1 of the 8x8), pools 2x2 -> float4 at
//              k_local = s_local*16 + hp*4.
// Compute id : n_c = tid&7, fg = (tid>>3)&15 (3 f's), kt = tid>>7 (k half).
//              Per chunk: 16 k-steps x (1 P-lds b128 + 3 W global b128 +
//              12 FMA). k-halves merged once at the end via LDS.
// ---------------------------------------------------------------------------
__global__ __launch_bounds__(256, 6)
void dwt_feat_main(const float* __restrict__ x,
                   const float* __restrict__ Weff,
                   const float* __restrict__ conv_b,
                   float* __restrict__ out, int n_total) {
  __shared__ __align__(16) float P_lds[2][TN][PROW];
  __shared__ float Mrg[TN][16][3];   // kt=1 partials

  const int tid = threadIdx.x;
  const int b   = blockIdx.x & 3;
  const int n0  = (blockIdx.x >> 2) * TN;
  if (n0 >= n_total) return;

  // staging identity
  const int sn      = tid >> 5;      // 0..7
  const int q       = tid & 31;
  const int s_local = q >> 2;        // 0..7
  const int hp      = q & 3;         // 0..3
  const float* xb = x + (size_t)(n0 + sn) * 32768 + (size_t)b * 8192
                    + s_local * 64 + hp * 16;
  const int pko = s_local * 16 + hp * 4;

  // compute identity
  const int n_c = tid & 7;
  const int fg  = (tid >> 3) & 15;   // 0..15
  const int kt  = tid >> 7;          // 0..1
  const float* wbase =
      Weff + ((size_t)b * NFEAT + fg * 3) * 2048 + kt * 64;

  float4 xr0, xr1, xr2, xr3;
  auto loadX = [&](int c) {
    const float* p = xb + c * 512;   // chunk = 8 time steps = 512 floats
    xr0 = *(const float4*)(p + 0);
    xr1 = *(const float4*)(p + 4);
    xr2 = *(const float4*)(p + 8);
    xr3 = *(const float4*)(p + 12);
  };
  auto poolStore = [&](int buf) {
    float4 pv;
    pv.x = fmaxf(fmaxf(xr0.x, xr0.y), fmaxf(xr2.x, xr2.y));
    pv.y = fmaxf(fmaxf(xr0.z, xr0.w), fmaxf(xr2.z, xr2.w));
    pv.z = fmaxf(fmaxf(xr1.x, xr1.y), fmaxf(xr3.x, xr3.y));
    pv.w = fmaxf(fmaxf(xr1.z, xr1.w), fmaxf(xr3.z, xr3.w));
    *(float4*)&P_lds[buf][sn][pko] = pv;
  };

  float acc0 = 0.f, acc1 = 0.f, acc2 = 0.f;

  loadX(0);
  poolStore(0);
  for (int c = 0; c < NCHUNK; ++c) {
    __syncthreads();                 // P[c&1] visible; frees P[(c+1)&1]
    if (c + 1 < NCHUNK) loadX(c + 1);
    const float* Pb = &P_lds[c & 1][n_c][kt * 64];
    const float* w0 = wbase + (size_t)c * CK;
    const float* w1 = w0 + 2048;
    const float* w2 = w0 + 4096;
    #pragma unroll 4
    for (int kk = 0; kk < 16; ++kk) {
      float4 p  = *(const float4*)(Pb + kk * 4);
      float4 wa = *(const float4*)(w0 + kk * 4);
      float4 wbv = *(const float4*)(w1 + kk * 4);
      float4 wc = *(const float4*)(w2 + kk * 4);
      acc0 += p.x * wa.x + p.y * wa.y + p.z * wa.z + p.w * wa.w;
      acc1 += p.x * wbv.x + p.y * wbv.y + p.z * wbv.z + p.w * wbv.w;
      acc2 += p.x * wc.x + p.y * wc.y + p.z * wc.z + p.w * wc.w;
    }
    if (c + 1 < NCHUNK) poolStore((c + 1) & 1);
  }

  // merge k-halves, bias + leaky-relu, store
  if (kt == 1) {
    Mrg[n_c][fg][0] = acc0;
    Mrg[n_c][fg][1] = acc1;
    Mrg[n_c][fg][2] = acc2;
  }
  __syncthreads();
  if (kt == 0) {
    const float* bias = conv_b + b * NFEAT + fg * 3;
    float* o = out + (size_t)(n0 + n_c) * (NBINS * NFEAT) + b * NFEAT + fg * 3;
    float v0 = acc0 + Mrg[n_c][fg][0] + bias[0];
    float v1 = acc1 + Mrg[n_c][fg][1] + bias[1];
    float v2 = acc2 + Mrg[n_c][fg][2] + bias[2];
    o[0] = v0 > 0.f ? v0 : 0.02f * v0;
    o[1] = v1 > 0.f ? v1 : 0.02f * v1;
    o[2] = v2 > 0.f ? v2 : 0.02f * v2;
  }
}

extern "C" void kernel_launch(void* const* d_in, const int* in_sizes, int n_in,
                              void* d_out, int out_size, void* d_ws, size_t ws_size,
                              hipStream_t stream) {
  const float* x      = (const float*)d_in[0]; // (n,1,512,8,8)
  const float* conv_w = (const float*)d_in[1]; // (4,48,154,4,4)
  const float* conv_b = (const float*)d_in[2]; // (4,48)
  float* out = (float*)d_out;

  float* D    = (float*)d_ws;            // 154*128 floats = 77 KB
  float* Weff = (float*)d_ws + 32768;    // at 128 KB offset; 1.5 MB

  int n = in_sizes[0] / 32768; // 2048

  build_dwt_matrix<<<2, 64, 0, stream>>>(D);
  build_weff<<<NBINS * NFEAT, 256, 0, stream>>>(conv_w, D, Weff);
  dwt_feat_main<<<(n / TN) * NBINS, 256, 0, stream>>>(x, Weff, conv_b, out, n);
}